// Round 15
// baseline (29.151 us; speedup 1.0000x reference)
//
#include <hip/hip_runtime.h>

#define WINDOW 11
#define H 512
#define W 512
#define OH 502            // H - WINDOW + 1
#define OW 502
#define NCH 3
#define BATCH 8
#define RSTRIPE 33        // 3 x 11 -> FIFO slot = unroll index (static)
#define NSTRIPES 16       // 15 x 33 rows + 1 x 7 live rows (one masked pass)
#define NGRP 5            // col groups: 4 x 118 outputs + 1 x 30 (float2 lanes)
#define GRPW 118          // output cols per full group (64 lanes * 2 - 10 halo)
#define WAVES_PER_IMG (NSTRIPES * NGRP)                 // 80
#define NWAVES (BATCH * NCH * WAVES_PER_IMG)            // 1920
#define WAVES_PER_BATCH (NCH * WAVES_PER_IMG)           // 240
#define NXCD 8
#define CHUNK (NWAVES / NXCD)                           // 240 = one batch per XCD

#define NPIX_PER_BATCH (3.0f * 502.0f * 502.0f)   // 756012

// Non-temporal (streaming, no-allocate) float2 load: avoids evicting the
// harness's 256MB of dirty poison lines from L3 on every read miss.
typedef float v2f __attribute__((ext_vector_type(2)));
__device__ __forceinline__ float2 ntload2(const float* p) {
    v2f v = __builtin_nontemporal_load((const v2f*)p);
    return make_float2(v.x, v.y);
}

// ---- gfx9 DPP inclusive wave scan (64 lanes), VALU-pipe only ----
template <int CTRL, int RM>
__device__ __forceinline__ float scan_step(float x) {
    int s = __builtin_amdgcn_update_dpp(0, __builtin_bit_cast(int, x),
                                        CTRL, RM, 0xf, false);
    return x + __builtin_bit_cast(float, s);
}
__device__ __forceinline__ float wave_iscan(float x) {
    x = scan_step<0x111, 0xf>(x);   // row_shr:1
    x = scan_step<0x112, 0xf>(x);   // row_shr:2
    x = scan_step<0x114, 0xf>(x);   // row_shr:4
    x = scan_step<0x118, 0xf>(x);   // row_shr:8
    x = scan_step<0x142, 0xa>(x);   // row_bcast:15 -> rows 1,3
    x = scan_step<0x143, 0xc>(x);   // row_bcast:31 -> rows 2,3
    return x;
}

__device__ __forceinline__ float ssim_from(float sx, float sy, float s2, float sxy) {
    const float n = 121.0f;
    const float inv_n = 1.0f / 121.0f;
    const float inv_nm1 = 1.0f / 120.0f;
    const float c1 = 1e-4f;   // (0.01)^2
    const float c2 = 9e-4f;   // (0.03)^2
    float mx  = sx * inv_n;
    float my  = sy * inv_n;
    float mxy = mx * my;
    float m2  = mx * mx + my * my;
    float cov = (sxy - n * mxy) * inv_nm1;   // covariance
    float v2  = (s2  - n * m2)  * inv_nm1;   // vx + vy
    float num = (2.f * mxy + c1) * (2.f * cov + c2);
    float den = (m2 + c1) * (v2 + c2);
    return num * __builtin_amdgcn_rcpf(den);  // den >= 9e-8, rel err ~1e-7
}

__global__ __launch_bounds__(64) void ssim_main(const float* __restrict__ x,
                                                const float* __restrict__ y,
                                                float* __restrict__ partials) {
    const int lane = threadIdx.x & 63;

    // XCD-chunked bijective swizzle: one batch (3 images) per XCD.
    const int wg    = blockIdx.x;               // 0..1919, round-robins XCDs
    const int w_lin = (wg % NXCD) * CHUNK + wg / NXCD;

    const int img = w_lin / WAVES_PER_IMG;      // b*NCH + c
    const int rem = w_lin % WAVES_PER_IMG;
    const int grp = rem / NSTRIPES;
    const int rs  = rem % NSTRIPES;             // stripe minor -> L2-contiguous

    const int i0 = rs * RSTRIPE;
    const int i1 = min(i0 + RSTRIPE, OH);       // 33 rows; stripe 15: 7 live
    const int cstart = grp * GRPW;              // first staged/output col
    const int outw   = min(GRPW, OW - cstart);  // 118 or 30
    // clamped column pair: out-of-range lanes read real (unused) data
    const int c0 = min(cstart + 2 * lane, W - 2);
    const bool tapActive = (2 * lane < outw);

    const float* __restrict__ xc = x + (size_t)img * H * W + c0;
    const float* __restrict__ yc = y + (size_t)img * H * W + c0;

    // --- 11-row register FIFO: each input row is loaded exactly ONCE ---
    float2 fx[11], fy[11];
    float4 v0 = make_float4(0.f, 0.f, 0.f, 0.f);
    float4 v1 = make_float4(0.f, 0.f, 0.f, 0.f);
#pragma unroll
    for (int r = 0; r < WINDOW; ++r) {
        float2 a = ntload2(xc + (size_t)(i0 + r) * W);
        float2 b = ntload2(yc + (size_t)(i0 + r) * W);
        fx[r] = a; fy[r] = b;
        v0.x += a.x; v0.y += b.x; v0.z += a.x * a.x + b.x * b.x; v0.w += a.x * b.x;
        v1.x += a.y; v1.y += b.y; v1.z += a.y * a.y + b.y * b.y; v1.w += a.y * b.y;
    }

    // incoming row buffer (row i+11), loaded one iteration ahead
    float2 nx, ny;
#define LDNEW(j) do {                                                \
        int jc_ = min((j), H - 1);                                   \
        nx = ntload2(xc + (size_t)jc_ * W);                          \
        ny = ntload2(yc + (size_t)jc_ * W);                          \
    } while (0)

    // slide: old row from FIFO slot u (registers), new row from (nx, ny)
#define SLIDE(u) do {                                                 \
        v0.x += nx.x - fx[u].x;                                       \
        v0.y += ny.x - fy[u].x;                                       \
        v0.z += nx.x * nx.x + ny.x * ny.x                             \
              - fx[u].x * fx[u].x - fy[u].x * fy[u].x;                \
        v0.w += nx.x * ny.x - fx[u].x * fy[u].x;                      \
        v1.x += nx.y - fx[u].y;                                       \
        v1.y += ny.y - fy[u].y;                                       \
        v1.z += nx.y * nx.y + ny.y * ny.y                             \
              - fx[u].y * fx[u].y - fy[u].y * fy[u].y;                \
        v1.w += nx.y * ny.y - fx[u].y * fy[u].y;                      \
        fx[u] = nx; fy[u] = ny;                                       \
    } while (0)

    float acc = 0.f;

#define COMPUTE(rowActive) do {                                               \
        float Tx = v0.x + v1.x, Ty = v0.y + v1.y;                             \
        float Tz = v0.z + v1.z, Tw = v0.w + v1.w;                             \
        float Sx = wave_iscan(Tx), Sy = wave_iscan(Ty);                       \
        float Sz = wave_iscan(Tz), Sw = wave_iscan(Tw);                       \
        int src = lane + 5;                                                   \
        float Ax = __shfl(Sx, src, 64), Ay = __shfl(Sy, src, 64);             \
        float Az = __shfl(Sz, src, 64), Aw = __shfl(Sw, src, 64);             \
        float Bx = __shfl(v1.x, src, 64), By = __shfl(v1.y, src, 64);         \
        float Bz = __shfl(v1.z, src, 64), Bw = __shfl(v1.w, src, 64);         \
        if (tapActive & (rowActive)) {                                        \
            acc += ssim_from(Ax - Bx - Sx + Tx, Ay - By - Sy + Ty,            \
                             Az - Bz - Sz + Tz, Aw - Bw - Sw + Tw);           \
            acc += ssim_from(Ax - Sx + v1.x, Ay - Sy + v1.y,                  \
                             Az - Sz + v1.z, Aw - Sw + v1.w);                 \
        }                                                                     \
    } while (0)

    // --- main loop: unroll 11 so the FIFO slot index is static ---
    LDNEW(i0 + WINDOW);                   // prefetch first incoming row
    for (int base = i0; base < i1; base += 11) {
#pragma unroll
        for (int u = 0; u < 11; ++u) {
            const int i = base + u;
            COMPUTE(i < i1);              // window sums + SSIM for row i
            SLIDE(u);                     // retire row i, absorb row i+11
            LDNEW(i + WINDOW + 1);        // prefetch next incoming (clamped)
        }
    }

    // --- per-wave reduction (fixed order, deterministic), no atomics ---
    for (int off = 32; off > 0; off >>= 1)
        acc += __shfl_down(acc, off, 64);
    if (lane == 0) partials[w_lin] = acc;   // batch-contiguous layout
}

__global__ __launch_bounds__(256) void ssim_reduce(const float* __restrict__ partials,
                                                   float* __restrict__ out) {
    const int b = blockIdx.x;              // one block per batch element
    const int t = threadIdx.x;
    float s = 0.f;
    if (t < WAVES_PER_BATCH)               // 240 per batch
        s = partials[b * WAVES_PER_BATCH + t];
    for (int off = 32; off > 0; off >>= 1)
        s += __shfl_down(s, off, 64);
    __shared__ float red[4];
    int wid = t >> 6, lane = t & 63;
    if (lane == 0) red[wid] = s;
    __syncthreads();
    if (t == 0) {
        float tot = (red[0] + red[1]) + (red[2] + red[3]);
        out[b] = (1.0f - tot / NPIX_PER_BATCH) * 0.5f;
    }
}

extern "C" void kernel_launch(void* const* d_in, const int* in_sizes, int n_in,
                              void* d_out, int out_size, void* d_ws, size_t ws_size,
                              hipStream_t stream) {
    const float* x = (const float*)d_in[0];
    const float* y = (const float*)d_in[1];
    float* out      = (float*)d_out;
    float* partials = (float*)d_ws;   // 1920 floats, fully overwritten each call

    ssim_main<<<NWAVES, 64, 0, stream>>>(x, y, partials);
    ssim_reduce<<<BATCH, 256, 0, stream>>>(partials, out);
}

// Round 16
// 28.871 us; speedup vs baseline: 1.0097x; 1.0097x over previous
//
#include <hip/hip_runtime.h>

#define WINDOW 11
#define H 512
#define W 512
#define OH 502            // H - WINDOW + 1
#define OW 502
#define NCH 3
#define BATCH 8
#define RSTRIPE 33        // 3 x 11 -> FIFO slot = unroll index (static)
#define NSTRIPES 16       // 15 x 33 rows + 1 x 7 live rows (one masked pass)
#define NGRP 5            // col groups: 4 x 118 outputs + 1 x 30 (float2 lanes)
#define GRPW 118          // output cols per full group (64 lanes * 2 - 10 halo)
#define WAVES_PER_IMG (NSTRIPES * NGRP)                 // 80
#define NWAVES (BATCH * NCH * WAVES_PER_IMG)            // 1920
#define WAVES_PER_BATCH (NCH * WAVES_PER_IMG)           // 240
#define NXCD 8
#define CHUNK (NWAVES / NXCD)                           // 240 = one batch per XCD

#define NPIX_PER_BATCH (3.0f * 502.0f * 502.0f)   // 756012

// packed 2xf32: elementwise ops compile to v_pk_{add,mul,fma}_f32 on gfx950
typedef float v2f __attribute__((ext_vector_type(2)));

__global__ __launch_bounds__(64) void ssim_main(const float* __restrict__ x,
                                                const float* __restrict__ y,
                                                float* __restrict__ partials) {
    const int lane = threadIdx.x & 63;

    // XCD-chunked bijective swizzle: one batch (3 images) per XCD -> the only
    // remaining reuse (cross-stripe halo rows) is XCD-L2-local.
    const int wg    = blockIdx.x;               // 0..1919, round-robins XCDs
    const int w_lin = (wg % NXCD) * CHUNK + wg / NXCD;

    const int img = w_lin / WAVES_PER_IMG;      // b*NCH + c
    const int rem = w_lin % WAVES_PER_IMG;
    const int grp = rem / NSTRIPES;
    const int rs  = rem % NSTRIPES;             // stripe minor -> L2-contiguous

    const int i0 = rs * RSTRIPE;
    const int i1 = min(i0 + RSTRIPE, OH);       // 33 rows; stripe 15: 7 live
    const int cstart = grp * GRPW;              // first staged/output col
    const int outw   = min(GRPW, OW - cstart);  // 118 or 30 (always even)
    // clamped column pair: out-of-range lanes read real (unused) data
    const int c0 = min(cstart + 2 * lane, W - 2);
    const bool tapActive = (2 * lane < outw);

    const float* __restrict__ xc = x + (size_t)img * H * W + c0;
    const float* __restrict__ yc = y + (size_t)img * H * W + c0;

    // bpermute source lanes for the sliding-sum ladder (hoisted)
    const int s1 = lane + 1, s2 = lane + 2, s4 = lane + 4, s5 = lane + 5;

    // --- 11-row register FIFO: each input row is loaded exactly ONCE ---
    v2f fx[11], fy[11];
    // per-column-pair quantities {col 2l, col 2l+1}: sum x, sum y, sum x2+y2, sum xy
    v2f Qx = 0.f, Qy = 0.f, Qz = 0.f, Qw = 0.f;
#pragma unroll
    for (int r = 0; r < WINDOW; ++r) {
        v2f a = *(const v2f*)(xc + (size_t)(i0 + r) * W);
        v2f b = *(const v2f*)(yc + (size_t)(i0 + r) * W);
        fx[r] = a; fy[r] = b;
        Qx += a;
        Qy += b;
        Qz += a * a + b * b;
        Qw += a * b;
    }

    // incoming row (row i+11), loaded one iteration ahead
    v2f nx, ny;
#define LDNEW(j) do {                                                \
        int jc_ = min((j), H - 1);                                   \
        nx = *(const v2f*)(xc + (size_t)jc_ * W);                    \
        ny = *(const v2f*)(yc + (size_t)jc_ * W);                    \
    } while (0)

    // slide: old row from FIFO slot u (registers), new row from (nx, ny)
#define SLIDE(u) do {                                                 \
        Qx += nx - fx[u];                                             \
        Qy += ny - fy[u];                                             \
        Qz += nx * nx + ny * ny - fx[u] * fx[u] - fy[u] * fy[u];      \
        Qw += nx * ny - fx[u] * fy[u];                                \
        fx[u] = nx; fy[u] = ny;                                       \
    } while (0)

    float acc = 0.f;

    // 11-tap window sums from pair-sums T[l] = col[2l]+col[2l+1]:
    //   We[l] = T[l..l+4] + q0[l+5]   (cols 2l   .. 2l+10)
    //   Wo[l] = T[l+1..l+5] + q1[l]   (cols 2l+1 .. 2l+11)
    // via bpermute sliding-sum ladder (wraps feed only masked lanes >= 59)
#define LADDER(T, q0, q1, We, Wo) do {                                \
        float U1 = T + __shfl(T, s1, 64);                             \
        float U2 = U1 + __shfl(U1, s2, 64);                           \
        float S5 = U2 + __shfl(T, s4, 64);                            \
        float S6 = S5 + __shfl(T, s5, 64);                            \
        We = S5 + __shfl(q0, s5, 64);                                 \
        Wo = S6 - T + q1;                                             \
    } while (0)

#define COMPUTE(rowActive) do {                                               \
        float Tx = Qx.x + Qx.y, Ty = Qy.x + Qy.y;                             \
        float Tz = Qz.x + Qz.y, Tw = Qw.x + Qw.y;                             \
        float Wex, Wox, Wey, Woy, Wez, Woz, Wew, Wow;                         \
        LADDER(Tx, Qx.x, Qx.y, Wex, Wox);                                     \
        LADDER(Ty, Qy.x, Qy.y, Wey, Woy);                                     \
        LADDER(Tz, Qz.x, Qz.y, Wez, Woz);                                     \
        LADDER(Tw, Qw.x, Qw.y, Wew, Wow);                                     \
        v2f Wx = {Wex, Wox}, Wy = {Wey, Woy};                                 \
        v2f Wz = {Wez, Woz}, Ww = {Wew, Wow};                                 \
        /* packed SSIM for the {even, odd} window pair */                     \
        v2f mx  = Wx * (1.0f / 121.0f);                                       \
        v2f my  = Wy * (1.0f / 121.0f);                                       \
        v2f mxy = mx * my;                                                    \
        v2f m2  = mx * mx + my * my;                                          \
        v2f cov = (Ww - 121.0f * mxy) * (1.0f / 120.0f);                      \
        v2f vv  = (Wz - 121.0f * m2)  * (1.0f / 120.0f);                      \
        v2f num = (2.0f * mxy + 1e-4f) * (2.0f * cov + 9e-4f);                \
        v2f den = (m2 + 1e-4f) * (vv + 9e-4f);                                \
        float r = num.x * __builtin_amdgcn_rcpf(den.x)                        \
                + num.y * __builtin_amdgcn_rcpf(den.y);                       \
        acc += (tapActive & (rowActive)) ? r : 0.f;                           \
    } while (0)

    // --- main loop: unroll 11 so the FIFO slot index is static ---
    LDNEW(i0 + WINDOW);                   // prefetch first incoming row
    for (int base = i0; base < i1; base += 11) {
#pragma unroll
        for (int u = 0; u < 11; ++u) {
            const int i = base + u;
            COMPUTE(i < i1);              // window sums + SSIM for row i
            SLIDE(u);                     // retire row i, absorb row i+11
            LDNEW(i + WINDOW + 1);        // prefetch next incoming (clamped)
        }
    }

    // --- per-wave reduction (fixed order, deterministic), no atomics ---
    for (int off = 32; off > 0; off >>= 1)
        acc += __shfl_down(acc, off, 64);
    if (lane == 0) partials[w_lin] = acc;   // batch-contiguous layout
}

__global__ __launch_bounds__(256) void ssim_reduce(const float* __restrict__ partials,
                                                   float* __restrict__ out) {
    const int b = blockIdx.x;              // one block per batch element
    const int t = threadIdx.x;
    float s = 0.f;
    if (t < WAVES_PER_BATCH)               // 240 per batch
        s = partials[b * WAVES_PER_BATCH + t];
    for (int off = 32; off > 0; off >>= 1)
        s += __shfl_down(s, off, 64);
    __shared__ float red[4];
    int wid = t >> 6, lane = t & 63;
    if (lane == 0) red[wid] = s;
    __syncthreads();
    if (t == 0) {
        float tot = (red[0] + red[1]) + (red[2] + red[3]);
        out[b] = (1.0f - tot / NPIX_PER_BATCH) * 0.5f;
    }
}

extern "C" void kernel_launch(void* const* d_in, const int* in_sizes, int n_in,
                              void* d_out, int out_size, void* d_ws, size_t ws_size,
                              hipStream_t stream) {
    const float* x = (const float*)d_in[0];
    const float* y = (const float*)d_in[1];
    float* out      = (float*)d_out;
    float* partials = (float*)d_ws;   // 1920 floats, fully overwritten each call

    ssim_main<<<NWAVES, 64, 0, stream>>>(x, y, partials);
    ssim_reduce<<<BATCH, 256, 0, stream>>>(partials, out);
}

// Round 17
// 25.813 us; speedup vs baseline: 1.1293x; 1.1185x over previous
//
#include <hip/hip_runtime.h>

#define WINDOW 11
#define H 512
#define W 512
#define OH 502            // H - WINDOW + 1
#define OW 502
#define NCH 3
#define BATCH 8
#define RSTRIPE 11        // one unrolled 11-pass; FIFO slot = unroll index
#define NSTRIPES 46       // 45 x 11 rows + 1 x 7 live rows (masked)
#define NGRP 5            // col groups: 4 x 118 outputs + 1 x 30 (float2 lanes)
#define GRPW 118          // output cols per full group (64 lanes * 2 - 10 halo)
#define WAVES_PER_IMG (NSTRIPES * NGRP)                 // 230
#define NWAVES (BATCH * NCH * WAVES_PER_IMG)            // 5520
#define WAVES_PER_BATCH (NCH * WAVES_PER_IMG)           // 690
#define NXCD 8
#define CHUNK (NWAVES / NXCD)                           // 690 = one batch per XCD

#define NPIX_PER_BATCH (3.0f * 502.0f * 502.0f)   // 756012

// packed 2xf32: elementwise ops compile to v_pk_{add,mul,fma}_f32 on gfx950
typedef float v2f __attribute__((ext_vector_type(2)));

// ---- gfx9 DPP inclusive wave scan (64 lanes), VALU-pipe only, 4-cyc hops ----
template <int CTRL, int RM>
__device__ __forceinline__ float scan_step(float x) {
    int s = __builtin_amdgcn_update_dpp(0, __builtin_bit_cast(int, x),
                                        CTRL, RM, 0xf, false);
    return x + __builtin_bit_cast(float, s);
}
__device__ __forceinline__ float wave_iscan(float x) {
    x = scan_step<0x111, 0xf>(x);   // row_shr:1
    x = scan_step<0x112, 0xf>(x);   // row_shr:2
    x = scan_step<0x114, 0xf>(x);   // row_shr:4
    x = scan_step<0x118, 0xf>(x);   // row_shr:8
    x = scan_step<0x142, 0xa>(x);   // row_bcast:15 -> rows 1,3
    x = scan_step<0x143, 0xc>(x);   // row_bcast:31 -> rows 2,3
    return x;
}

__global__ __launch_bounds__(64) void ssim_main(const float* __restrict__ x,
                                                const float* __restrict__ y,
                                                float* __restrict__ partials) {
    const int lane = threadIdx.x & 63;

    // XCD-chunked bijective swizzle: one batch (3 images) per XCD -> halo
    // rows shared between stripes re-read XCD-L2-locally.
    const int wg    = blockIdx.x;               // 0..5519, round-robins XCDs
    const int w_lin = (wg % NXCD) * CHUNK + wg / NXCD;

    const int img = w_lin / WAVES_PER_IMG;      // b*NCH + c
    const int rem = w_lin % WAVES_PER_IMG;
    const int grp = rem / NSTRIPES;
    const int rs  = rem % NSTRIPES;             // stripe minor -> L2-contiguous

    const int i0 = rs * RSTRIPE;
    const int i1 = min(i0 + RSTRIPE, OH);       // 11 rows; stripe 45: 7 live
    const int cstart = grp * GRPW;              // first staged/output col
    const int outw   = min(GRPW, OW - cstart);  // 118 or 30
    // clamped column pair: out-of-range lanes read real (unused) data
    const int c0 = min(cstart + 2 * lane, W - 2);
    const bool tapActive = (2 * lane < outw);

    const float* __restrict__ xc = x + (size_t)img * H * W + c0;
    const float* __restrict__ yc = y + (size_t)img * H * W + c0;

    // --- 11-row register FIFO: each input row loaded exactly ONCE ---
    v2f fx[11], fy[11];
    // per-column-pair sums {col 2l, col 2l+1}: x, y, x2+y2, xy
    v2f Qx = 0.f, Qy = 0.f, Qz = 0.f, Qw = 0.f;
#pragma unroll
    for (int r = 0; r < WINDOW; ++r) {
        v2f a = *(const v2f*)(xc + (size_t)(i0 + r) * W);
        v2f b = *(const v2f*)(yc + (size_t)(i0 + r) * W);
        fx[r] = a; fy[r] = b;
        Qx += a;
        Qy += b;
        Qz += a * a + b * b;
        Qw += a * b;
    }

    // incoming row (row i+11), loaded one iteration ahead
    v2f nx, ny;
#define LDNEW(j) do {                                                \
        int jc_ = min((j), H - 1);                                   \
        nx = *(const v2f*)(xc + (size_t)jc_ * W);                    \
        ny = *(const v2f*)(yc + (size_t)jc_ * W);                    \
    } while (0)

    // packed slide: old row from FIFO slot u, new row from (nx, ny)
#define SLIDE(u) do {                                                 \
        Qx += nx - fx[u];                                             \
        Qy += ny - fy[u];                                             \
        Qz += nx * nx + ny * ny - fx[u] * fx[u] - fy[u] * fy[u];      \
        Qw += nx * ny - fx[u] * fy[u];                                \
        fx[u] = nx; fy[u] = ny;                                       \
    } while (0)

    float acc = 0.f;

    // window sums via DPP scan over pair-totals T, then lane+5 fetches:
    //   We[l] = (S[l+5]-q1[l+5]) - (S[l]-T[l])    (cols 2l..2l+10)
    //   Wo[l] =  S[l+5] - S[l] + q1[l]            (cols 2l+1..2l+11)
#define COMPUTE(rowActive) do {                                               \
        float Tx = Qx.x + Qx.y, Ty = Qy.x + Qy.y;                             \
        float Tz = Qz.x + Qz.y, Tw = Qw.x + Qw.y;                             \
        float Sx = wave_iscan(Tx), Sy = wave_iscan(Ty);                       \
        float Sz = wave_iscan(Tz), Sw = wave_iscan(Tw);                       \
        int src = lane + 5;                                                   \
        float Ax = __shfl(Sx, src, 64), Ay = __shfl(Sy, src, 64);             \
        float Az = __shfl(Sz, src, 64), Aw = __shfl(Sw, src, 64);             \
        float Bx = __shfl(Qx.y, src, 64), By = __shfl(Qy.y, src, 64);         \
        float Bz = __shfl(Qz.y, src, 64), Bw = __shfl(Qw.y, src, 64);         \
        v2f Wx = {Ax - Bx - Sx + Tx, Ax - Sx + Qx.y};                         \
        v2f Wy = {Ay - By - Sy + Ty, Ay - Sy + Qy.y};                         \
        v2f Wz = {Az - Bz - Sz + Tz, Az - Sz + Qz.y};                         \
        v2f Ww = {Aw - Bw - Sw + Tw, Aw - Sw + Qw.y};                         \
        /* packed SSIM for the {even, odd} window pair */                     \
        v2f mx  = Wx * (1.0f / 121.0f);                                       \
        v2f my  = Wy * (1.0f / 121.0f);                                       \
        v2f mxy = mx * my;                                                    \
        v2f m2  = mx * mx + my * my;                                          \
        v2f cov = (Ww - 121.0f * mxy) * (1.0f / 120.0f);                      \
        v2f vv  = (Wz - 121.0f * m2)  * (1.0f / 120.0f);                      \
        v2f num = (2.0f * mxy + 1e-4f) * (2.0f * cov + 9e-4f);                \
        v2f den = (m2 + 1e-4f) * (vv + 9e-4f);                                \
        float r = num.x * __builtin_amdgcn_rcpf(den.x)                        \
                + num.y * __builtin_amdgcn_rcpf(den.y);                       \
        acc += (tapActive & (rowActive)) ? r : 0.f;                           \
    } while (0)

    // --- single unrolled 11-pass: FIFO slot index is the unroll index ---
    LDNEW(i0 + WINDOW);                   // prefetch first incoming row
#pragma unroll
    for (int u = 0; u < 11; ++u) {
        const int i = i0 + u;
        COMPUTE(i < i1);                  // window sums + SSIM for row i
        SLIDE(u);                         // retire row i, absorb row i+11
        LDNEW(i + WINDOW + 1);            // prefetch next incoming (clamped)
    }

    // --- per-wave reduction (fixed order, deterministic), no atomics ---
    for (int off = 32; off > 0; off >>= 1)
        acc += __shfl_down(acc, off, 64);
    if (lane == 0) partials[w_lin] = acc;   // batch-contiguous layout
}

__global__ __launch_bounds__(256) void ssim_reduce(const float* __restrict__ partials,
                                                   float* __restrict__ out) {
    const int b = blockIdx.x;              // one block per batch element
    const int t = threadIdx.x;
    float s = 0.f;
    for (int k = t; k < WAVES_PER_BATCH; k += 256)   // 690 per batch
        s += partials[b * WAVES_PER_BATCH + k];
    for (int off = 32; off > 0; off >>= 1)
        s += __shfl_down(s, off, 64);
    __shared__ float red[4];
    int wid = t >> 6, lane = t & 63;
    if (lane == 0) red[wid] = s;
    __syncthreads();
    if (t == 0) {
        float tot = (red[0] + red[1]) + (red[2] + red[3]);
        out[b] = (1.0f - tot / NPIX_PER_BATCH) * 0.5f;
    }
}

extern "C" void kernel_launch(void* const* d_in, const int* in_sizes, int n_in,
                              void* d_out, int out_size, void* d_ws, size_t ws_size,
                              hipStream_t stream) {
    const float* x = (const float*)d_in[0];
    const float* y = (const float*)d_in[1];
    float* out      = (float*)d_out;
    float* partials = (float*)d_ws;   // 5520 floats, fully overwritten each call

    ssim_main<<<NWAVES, 64, 0, stream>>>(x, y, partials);
    ssim_reduce<<<BATCH, 256, 0, stream>>>(partials, out);
}